// Round 1
// baseline (11747.108 us; speedup 1.0000x reference)
//
#include <hip/hip_runtime.h>

#define N_NODES 100000
#define N_EDGES 1600000
#define N_GRAPHS 1024
#define HID 128
#define LAYERS 4
#define LN_EPS 1e-5f

// ---------------- input projection: h = x @ inW + inb ----------------
__global__ __launch_bounds__(256) void k_input_proj(
    const float* __restrict__ x, const float* __restrict__ inW,
    const float* __restrict__ inb, float* __restrict__ h) {
    int idx = blockIdx.x * 256 + threadIdx.x;  // over N_NODES*HID (exact)
    int n = idx >> 7, c = idx & 127;
    const float* xr = x + n * 7;
    float s = inb[c];
#pragma unroll
    for (int k = 0; k < 7; ++k) s += xr[k] * inW[k * HID + c];
    h[idx] = s;
}

// ------------- edge message + scatter-add into agg -------------------
// 256 threads = 8 edge-slots x 32 col-lanes (4 cols each). Each slot
// processes 4 edges -> 32 edges/block, 50000 blocks (exact).
__global__ __launch_bounds__(256) void k_edge_scatter(
    const int* __restrict__ ei, const float* __restrict__ ea,
    const float* __restrict__ eW, const float* __restrict__ eb,
    const float* __restrict__ h, float* __restrict__ agg) {
    const int lane = threadIdx.x & 31;
    const int slot = threadIdx.x >> 5;
    const int c0 = lane * 4;
    // per-thread edge-projection weights (constant over edges)
    const float4 w0 = *(const float4*)(eW + 0 * HID + c0);
    const float4 w1 = *(const float4*)(eW + 1 * HID + c0);
    const float4 w2 = *(const float4*)(eW + 2 * HID + c0);
    const float4 bb = *(const float4*)(eb + c0);
    const int ebase = blockIdx.x * 32 + slot;
#pragma unroll
    for (int i = 0; i < 4; ++i) {
        const int e = ebase + i * 8;
        const int src = ei[e];
        const int dst = ei[N_EDGES + e];
        const float a0 = ea[e * 3 + 0];
        const float a1 = ea[e * 3 + 1];
        const float a2 = ea[e * 3 + 2];
        const float4 hv = *(const float4*)(h + (long)src * HID + c0);
        float m0 = fmaxf(hv.x + a0 * w0.x + a1 * w1.x + a2 * w2.x + bb.x, 0.f);
        float m1 = fmaxf(hv.y + a0 * w0.y + a1 * w1.y + a2 * w2.y + bb.y, 0.f);
        float m2 = fmaxf(hv.z + a0 * w0.z + a1 * w1.z + a2 * w2.z + bb.z, 0.f);
        float m3 = fmaxf(hv.w + a0 * w0.w + a1 * w1.w + a2 * w2.w + bb.w, 0.f);
        float* ap = agg + (long)dst * HID + c0;
        atomicAdd(ap + 0, m0);
        atomicAdd(ap + 1, m1);
        atomicAdd(ap + 2, m2);
        atomicAdd(ap + 3, m3);
    }
}

// --------- fused node MLP + residual + layernorm (in-place h) --------
// Block = 256 threads handles 32 nodes. LDS tiles padded to 129 floats.
__global__ __launch_bounds__(256) void k_node_update(
    const float* __restrict__ agg, float* __restrict__ h,
    const float* __restrict__ w1, const float* __restrict__ b1,
    const float* __restrict__ w2, const float* __restrict__ b2,
    const float* __restrict__ gamma, const float* __restrict__ beta) {
    __shared__ float gt[32][HID + 1];
    __shared__ float t1[32][HID + 1];
    const int n0 = blockIdx.x * 32;
    // phase 1: g = agg + h into LDS
    for (int i = threadIdx.x; i < 32 * HID; i += 256) {
        int n = i >> 7, c = i & 127;
        int gidx = (n0 + n) * HID + c;
        gt[n][c] = agg[gidx] + h[gidx];
    }
    __syncthreads();

    const int tx = threadIdx.x & 31;  // cols 4tx..4tx+3
    const int ty = threadIdx.x >> 5;  // nodes ty, ty+8, ty+16, ty+24
    const int j0 = tx * 4;

    // phase 2: t1 = relu(g @ w1 + b1)
    {
        float acc[4][4];
        const float4 bv = *(const float4*)(b1 + j0);
#pragma unroll
        for (int r = 0; r < 4; ++r) {
            acc[r][0] = bv.x; acc[r][1] = bv.y; acc[r][2] = bv.z; acc[r][3] = bv.w;
        }
        for (int k = 0; k < HID; ++k) {
            const float4 w = *(const float4*)(w1 + k * HID + j0);
#pragma unroll
            for (int r = 0; r < 4; ++r) {
                const float gk = gt[ty + 8 * r][k];
                acc[r][0] += gk * w.x;
                acc[r][1] += gk * w.y;
                acc[r][2] += gk * w.z;
                acc[r][3] += gk * w.w;
            }
        }
#pragma unroll
        for (int r = 0; r < 4; ++r) {
            float* tp = &t1[ty + 8 * r][j0];
            tp[0] = fmaxf(acc[r][0], 0.f);
            tp[1] = fmaxf(acc[r][1], 0.f);
            tp[2] = fmaxf(acc[r][2], 0.f);
            tp[3] = fmaxf(acc[r][3], 0.f);
        }
    }
    __syncthreads();

    // phase 3: u = h + relu(t1 @ w2 + b2), stored back into gt
    {
        float acc[4][4];
        const float4 bv = *(const float4*)(b2 + j0);
#pragma unroll
        for (int r = 0; r < 4; ++r) {
            acc[r][0] = bv.x; acc[r][1] = bv.y; acc[r][2] = bv.z; acc[r][3] = bv.w;
        }
        for (int k = 0; k < HID; ++k) {
            const float4 w = *(const float4*)(w2 + k * HID + j0);
#pragma unroll
            for (int r = 0; r < 4; ++r) {
                const float tk = t1[ty + 8 * r][k];
                acc[r][0] += tk * w.x;
                acc[r][1] += tk * w.y;
                acc[r][2] += tk * w.z;
                acc[r][3] += tk * w.w;
            }
        }
#pragma unroll
        for (int r = 0; r < 4; ++r) {
            const int n = ty + 8 * r;
            const float4 hv = *(const float4*)(h + (n0 + n) * HID + j0);
            gt[n][j0 + 0] = hv.x + fmaxf(acc[r][0], 0.f);
            gt[n][j0 + 1] = hv.y + fmaxf(acc[r][1], 0.f);
            gt[n][j0 + 2] = hv.z + fmaxf(acc[r][2], 0.f);
            gt[n][j0 + 3] = hv.w + fmaxf(acc[r][3], 0.f);
        }
    }
    __syncthreads();

    // phase 4: layernorm, 8 threads per node
    {
        const int node = threadIdx.x >> 3;
        const int sub = threadIdx.x & 7;
        float s = 0.f, s2 = 0.f;
        for (int c = sub; c < HID; c += 8) {
            const float v = gt[node][c];
            s += v;
            s2 += v * v;
        }
#pragma unroll
        for (int off = 1; off < 8; off <<= 1) {
            s += __shfl_xor(s, off);
            s2 += __shfl_xor(s2, off);
        }
        const float mu = s * (1.f / HID);
        const float var = s2 * (1.f / HID) - mu * mu;
        const float inv = rsqrtf(var + LN_EPS);
        for (int c = sub; c < HID; c += 8) {
            h[(n0 + node) * HID + c] = (gt[node][c] - mu) * inv * gamma[c] + beta[c];
        }
    }
}

// ---------------- global mean pool (atomic) --------------------------
__global__ __launch_bounds__(256) void k_pool(
    const float* __restrict__ h, const int* __restrict__ batch,
    float* __restrict__ sums, float* __restrict__ cnt) {
    int idx = blockIdx.x * 256 + threadIdx.x;  // over N_NODES*32 (exact)
    int n = idx >> 5, cg = idx & 31;
    int b = batch[n];
    const float4 v = *(const float4*)(h + (long)n * HID + cg * 4);
    float* sp = sums + (long)b * HID + cg * 4;
    atomicAdd(sp + 0, v.x);
    atomicAdd(sp + 1, v.y);
    atomicAdd(sp + 2, v.z);
    atomicAdd(sp + 3, v.w);
    if (cg == 0) atomicAdd(&cnt[b], 1.0f);
}

// ---------------- head: 1 block per graph ----------------------------
__global__ __launch_bounds__(128) void k_head(
    const float* __restrict__ sums, const float* __restrict__ cnt,
    const float* __restrict__ fcW1, const float* __restrict__ fcb1,
    const float* __restrict__ fcW2, const float* __restrict__ fcb2,
    const float* __restrict__ fcW3, const float* __restrict__ fcb3,
    float* __restrict__ out) {
    __shared__ float p[HID];
    __shared__ float o1[HID];
    __shared__ float o2[64];
    const int g = blockIdx.x, t = threadIdx.x;
    const float c = fmaxf(cnt[g], 1.0f);
    p[t] = sums[g * HID + t] / c;
    __syncthreads();
    float s = fcb1[t];
    for (int k = 0; k < HID; ++k) s += p[k] * fcW1[k * HID + t];
    o1[t] = fmaxf(s, 0.f);
    __syncthreads();
    if (t < 64) {
        float s2 = fcb2[t];
        for (int k = 0; k < HID; ++k) s2 += o1[k] * fcW2[k * 64 + t];
        o2[t] = fmaxf(s2, 0.f);
    }
    __syncthreads();
    if (t < 64) {
        float v = o2[t] * fcW3[t];
#pragma unroll
        for (int off = 32; off > 0; off >>= 1) v += __shfl_down(v, off);
        if (t == 0) out[g] = v + fcb3[0];
    }
}

extern "C" void kernel_launch(void* const* d_in, const int* in_sizes, int n_in,
                              void* d_out, int out_size, void* d_ws, size_t ws_size,
                              hipStream_t stream) {
    const float* x    = (const float*)d_in[0];
    const int*   ei   = (const int*)d_in[1];
    const float* ea   = (const float*)d_in[2];
    const int*   batch= (const int*)d_in[3];
    const float* inW  = (const float*)d_in[4];
    const float* inb  = (const float*)d_in[5];
    const float* edgeW= (const float*)d_in[6];
    const float* edgeb= (const float*)d_in[7];
    const float* w1   = (const float*)d_in[8];
    const float* b1   = (const float*)d_in[9];
    const float* w2   = (const float*)d_in[10];
    const float* b2   = (const float*)d_in[11];
    const float* gamma= (const float*)d_in[12];
    const float* beta = (const float*)d_in[13];
    const float* fcW1 = (const float*)d_in[14];
    const float* fcb1 = (const float*)d_in[15];
    const float* fcW2 = (const float*)d_in[16];
    const float* fcb2 = (const float*)d_in[17];
    const float* fcW3 = (const float*)d_in[18];
    const float* fcb3 = (const float*)d_in[19];
    float* out = (float*)d_out;

    float* h    = (float*)d_ws;
    float* agg  = h + (size_t)N_NODES * HID;
    float* sums = agg + (size_t)N_NODES * HID;
    float* cnt  = sums + (size_t)N_GRAPHS * HID;

    // zero pool accumulators (ws is poisoned before every launch)
    hipMemsetAsync(sums, 0, ((size_t)N_GRAPHS * HID + N_GRAPHS) * sizeof(float), stream);

    k_input_proj<<<(N_NODES * HID) / 256, 256, 0, stream>>>(x, inW, inb, h);

    for (int l = 0; l < LAYERS; ++l) {
        hipMemsetAsync(agg, 0, (size_t)N_NODES * HID * sizeof(float), stream);
        k_edge_scatter<<<N_EDGES / 32, 256, 0, stream>>>(
            ei, ea, edgeW + l * 3 * HID, edgeb + l * HID, h, agg);
        k_node_update<<<N_NODES / 32, 256, 0, stream>>>(
            agg, h, w1 + l * HID * HID, b1 + l * HID,
            w2 + l * HID * HID, b2 + l * HID, gamma + l * HID, beta + l * HID);
    }

    k_pool<<<(N_NODES * 32) / 256, 256, 0, stream>>>(h, batch, sums, cnt);
    k_head<<<N_GRAPHS, 128, 0, stream>>>(sums, cnt, fcW1, fcb1, fcW2, fcb2,
                                         fcW3, fcb3, out);
}

// Round 2
// 2344.741 us; speedup vs baseline: 5.0100x; 5.0100x over previous
//
#include <hip/hip_runtime.h>

#define N_NODES 100000
#define N_EDGES 1600000
#define N_GRAPHS 1024
#define HID 128
#define LAYERS 4
#define LN_EPS 1e-5f
#define SCAN_THREADS 1024
#define SCAN_CHUNK 98  // ceil(100000/1024)

// ---------------- input projection: h = x @ inW + inb ----------------
__global__ __launch_bounds__(256) void k_input_proj(
    const float* __restrict__ x, const float* __restrict__ inW,
    const float* __restrict__ inb, float* __restrict__ h) {
    int idx = blockIdx.x * 256 + threadIdx.x;  // over N_NODES*HID (exact)
    int n = idx >> 7, c = idx & 127;
    const float* xr = x + n * 7;
    float s = inb[c];
#pragma unroll
    for (int k = 0; k < 7; ++k) s += xr[k] * inW[k * HID + c];
    h[idx] = s;
}

// ---------------- CSR build: histogram of dst ------------------------
__global__ __launch_bounds__(256) void k_hist(
    const int* __restrict__ ei, int* __restrict__ deg) {
    int e = blockIdx.x * 256 + threadIdx.x;  // N_EDGES exact
    atomicAdd(&deg[ei[N_EDGES + e]], 1);
}

// ---------------- CSR build: single-block exclusive scan -------------
// deg (=cursor array) in, row_ptr + reset cursor out.
__global__ __launch_bounds__(SCAN_THREADS) void k_scan(
    int* __restrict__ cursor, int* __restrict__ row_ptr) {
    __shared__ int part[SCAN_THREADS];
    const int t = threadIdx.x;
    const int base = t * SCAN_CHUNK;
    int s = 0;
    for (int i = 0; i < SCAN_CHUNK; ++i) {
        int idx = base + i;
        if (idx < N_NODES) s += cursor[idx];
    }
    part[t] = s;
    __syncthreads();
    for (int off = 1; off < SCAN_THREADS; off <<= 1) {
        int v = 0;
        if (t >= off) v = part[t - off];
        __syncthreads();
        if (t >= off) part[t] += v;
        __syncthreads();
    }
    int run = (t == 0) ? 0 : part[t - 1];
    for (int i = 0; i < SCAN_CHUNK; ++i) {
        int idx = base + i;
        if (idx < N_NODES) {
            int d = cursor[idx];
            row_ptr[idx] = run;
            cursor[idx] = run;
            run += d;
        }
    }
    if (t == 0) row_ptr[N_NODES] = N_EDGES;
}

// ---------------- CSR build: scatter edges into sorted slots ---------
__global__ __launch_bounds__(256) void k_scatter(
    const int* __restrict__ ei, const float* __restrict__ ea,
    int* __restrict__ cursor, float4* __restrict__ edata) {
    int e = blockIdx.x * 256 + threadIdx.x;  // N_EDGES exact
    const int src = ei[e];
    const int dst = ei[N_EDGES + e];
    const int pos = atomicAdd(&cursor[dst], 1);
    edata[pos] = make_float4(ea[e * 3 + 0], ea[e * 3 + 1], ea[e * 3 + 2],
                             __int_as_float(src));
}

// ------- fused gather-aggregate + MLP + residual + layernorm ---------
// Block = 256 threads (4 waves) handles 32 nodes. Reads hin, writes hout.
__global__ __launch_bounds__(256) void k_node_update(
    const float4* __restrict__ edata, const int* __restrict__ row_ptr,
    const float* __restrict__ eW, const float* __restrict__ eb,
    const float* __restrict__ hin, float* __restrict__ hout,
    const float* __restrict__ w1, const float* __restrict__ b1,
    const float* __restrict__ w2, const float* __restrict__ b2,
    const float* __restrict__ gamma, const float* __restrict__ beta) {
    __shared__ float gt[32][HID + 1];
    __shared__ float t1[32][HID + 1];
    const int n0 = blockIdx.x * 32;

    // phase 1: gt[n] = hin[n] + sum_{e into n} relu(hin[src] + edgeproj(e))
    {
        const int wave = threadIdx.x >> 6;
        const int lane = threadIdx.x & 63;
        const int c2 = lane * 2;
        const float2 ew0 = *(const float2*)(eW + 0 * HID + c2);
        const float2 ew1 = *(const float2*)(eW + 1 * HID + c2);
        const float2 ew2 = *(const float2*)(eW + 2 * HID + c2);
        const float2 ebv = *(const float2*)(eb + c2);
        for (int s = 0; s < 8; ++s) {
            const int ln = wave * 8 + s;
            const int n = n0 + ln;
            const float2 hv0 = *(const float2*)(hin + (long)n * HID + c2);
            float ax = hv0.x, ay = hv0.y;
            const int e0 = row_ptr[n], e1 = row_ptr[n + 1];
            for (int e = e0; e < e1; ++e) {
                const float4 ed = edata[e];
                const int src = __float_as_int(ed.w);
                const float2 hv = *(const float2*)(hin + (long)src * HID + c2);
                ax += fmaxf(hv.x + ed.x * ew0.x + ed.y * ew1.x + ed.z * ew2.x + ebv.x, 0.f);
                ay += fmaxf(hv.y + ed.x * ew0.y + ed.y * ew1.y + ed.z * ew2.y + ebv.y, 0.f);
            }
            gt[ln][c2] = ax;
            gt[ln][c2 + 1] = ay;
        }
    }
    __syncthreads();

    const int tx = threadIdx.x & 31;  // cols 4tx..4tx+3
    const int ty = threadIdx.x >> 5;  // nodes ty, ty+8, ty+16, ty+24
    const int j0 = tx * 4;

    // phase 2: t1 = relu(g @ w1 + b1)
    {
        float acc[4][4];
        const float4 bv = *(const float4*)(b1 + j0);
#pragma unroll
        for (int r = 0; r < 4; ++r) {
            acc[r][0] = bv.x; acc[r][1] = bv.y; acc[r][2] = bv.z; acc[r][3] = bv.w;
        }
        for (int k = 0; k < HID; ++k) {
            const float4 w = *(const float4*)(w1 + k * HID + j0);
#pragma unroll
            for (int r = 0; r < 4; ++r) {
                const float gk = gt[ty + 8 * r][k];
                acc[r][0] += gk * w.x;
                acc[r][1] += gk * w.y;
                acc[r][2] += gk * w.z;
                acc[r][3] += gk * w.w;
            }
        }
#pragma unroll
        for (int r = 0; r < 4; ++r) {
            float* tp = &t1[ty + 8 * r][j0];
            tp[0] = fmaxf(acc[r][0], 0.f);
            tp[1] = fmaxf(acc[r][1], 0.f);
            tp[2] = fmaxf(acc[r][2], 0.f);
            tp[3] = fmaxf(acc[r][3], 0.f);
        }
    }
    __syncthreads();

    // phase 3: u = hin + relu(t1 @ w2 + b2), stored back into gt
    {
        float acc[4][4];
        const float4 bv = *(const float4*)(b2 + j0);
#pragma unroll
        for (int r = 0; r < 4; ++r) {
            acc[r][0] = bv.x; acc[r][1] = bv.y; acc[r][2] = bv.z; acc[r][3] = bv.w;
        }
        for (int k = 0; k < HID; ++k) {
            const float4 w = *(const float4*)(w2 + k * HID + j0);
#pragma unroll
            for (int r = 0; r < 4; ++r) {
                const float tk = t1[ty + 8 * r][k];
                acc[r][0] += tk * w.x;
                acc[r][1] += tk * w.y;
                acc[r][2] += tk * w.z;
                acc[r][3] += tk * w.w;
            }
        }
#pragma unroll
        for (int r = 0; r < 4; ++r) {
            const int n = ty + 8 * r;
            const float4 hv = *(const float4*)(hin + (n0 + n) * HID + j0);
            gt[n][j0 + 0] = hv.x + fmaxf(acc[r][0], 0.f);
            gt[n][j0 + 1] = hv.y + fmaxf(acc[r][1], 0.f);
            gt[n][j0 + 2] = hv.z + fmaxf(acc[r][2], 0.f);
            gt[n][j0 + 3] = hv.w + fmaxf(acc[r][3], 0.f);
        }
    }
    __syncthreads();

    // phase 4: layernorm, 8 threads per node, write hout
    {
        const int node = threadIdx.x >> 3;
        const int sub = threadIdx.x & 7;
        float s = 0.f, s2 = 0.f;
        for (int c = sub; c < HID; c += 8) {
            const float v = gt[node][c];
            s += v;
            s2 += v * v;
        }
#pragma unroll
        for (int off = 1; off < 8; off <<= 1) {
            s += __shfl_xor(s, off);
            s2 += __shfl_xor(s2, off);
        }
        const float mu = s * (1.f / HID);
        const float var = s2 * (1.f / HID) - mu * mu;
        const float inv = rsqrtf(var + LN_EPS);
        for (int c = sub; c < HID; c += 8) {
            hout[(n0 + node) * HID + c] = (gt[node][c] - mu) * inv * gamma[c] + beta[c];
        }
    }
}

// -------- global mean pool: segmented reduction (batch is sorted) ----
__global__ __launch_bounds__(128) void k_pool(
    const float* __restrict__ h, const int* __restrict__ batch,
    float* __restrict__ sums, float* __restrict__ cnt) {
    const int c = threadIdx.x;
    const int n0 = blockIdx.x * 128;
    if (n0 >= N_NODES) return;
    const int nend = min(n0 + 128, N_NODES);
    int cur = batch[n0];
    float acc = 0.f;
    int runlen = 0;
    for (int n = n0; n < nend; ++n) {
        const int b = batch[n];
        if (b != cur) {
            atomicAdd(&sums[(long)cur * HID + c], acc);
            if (c == 0) atomicAdd(&cnt[cur], (float)runlen);
            acc = 0.f;
            runlen = 0;
            cur = b;
        }
        acc += h[(long)n * HID + c];
        ++runlen;
    }
    atomicAdd(&sums[(long)cur * HID + c], acc);
    if (c == 0) atomicAdd(&cnt[cur], (float)runlen);
}

// ---------------- head: 1 block per graph ----------------------------
__global__ __launch_bounds__(128) void k_head(
    const float* __restrict__ sums, const float* __restrict__ cnt,
    const float* __restrict__ fcW1, const float* __restrict__ fcb1,
    const float* __restrict__ fcW2, const float* __restrict__ fcb2,
    const float* __restrict__ fcW3, const float* __restrict__ fcb3,
    float* __restrict__ out) {
    __shared__ float p[HID];
    __shared__ float o1[HID];
    __shared__ float o2[64];
    const int g = blockIdx.x, t = threadIdx.x;
    const float c = fmaxf(cnt[g], 1.0f);
    p[t] = sums[g * HID + t] / c;
    __syncthreads();
    float s = fcb1[t];
    for (int k = 0; k < HID; ++k) s += p[k] * fcW1[k * HID + t];
    o1[t] = fmaxf(s, 0.f);
    __syncthreads();
    if (t < 64) {
        float s2 = fcb2[t];
        for (int k = 0; k < HID; ++k) s2 += o1[k] * fcW2[k * 64 + t];
        o2[t] = fmaxf(s2, 0.f);
    }
    __syncthreads();
    if (t < 64) {
        float v = o2[t] * fcW3[t];
#pragma unroll
        for (int off = 32; off > 0; off >>= 1) v += __shfl_down(v, off);
        if (t == 0) out[g] = v + fcb3[0];
    }
}

extern "C" void kernel_launch(void* const* d_in, const int* in_sizes, int n_in,
                              void* d_out, int out_size, void* d_ws, size_t ws_size,
                              hipStream_t stream) {
    const float* x    = (const float*)d_in[0];
    const int*   ei   = (const int*)d_in[1];
    const float* ea   = (const float*)d_in[2];
    const int*   batch= (const int*)d_in[3];
    const float* inW  = (const float*)d_in[4];
    const float* inb  = (const float*)d_in[5];
    const float* edgeW= (const float*)d_in[6];
    const float* edgeb= (const float*)d_in[7];
    const float* w1   = (const float*)d_in[8];
    const float* b1   = (const float*)d_in[9];
    const float* w2   = (const float*)d_in[10];
    const float* b2   = (const float*)d_in[11];
    const float* gamma= (const float*)d_in[12];
    const float* beta = (const float*)d_in[13];
    const float* fcW1 = (const float*)d_in[14];
    const float* fcb1 = (const float*)d_in[15];
    const float* fcW2 = (const float*)d_in[16];
    const float* fcb2 = (const float*)d_in[17];
    const float* fcW3 = (const float*)d_in[18];
    const float* fcb3 = (const float*)d_in[19];
    float* out = (float*)d_out;

    // workspace layout (float4-aligned first): ~129.3 MB total
    float4* edata  = (float4*)d_ws;                               // 1.6M float4
    float*  h0     = (float*)(edata + N_EDGES);                   // 12.8M f32
    float*  h1     = h0 + (size_t)N_NODES * HID;                  // 12.8M f32
    int*    row_ptr= (int*)(h1 + (size_t)N_NODES * HID);          // 100001
    int*    cursor = row_ptr + (N_NODES + 1);                     // 100000
    float*  sums   = (float*)(cursor + N_NODES);                  // 1024*128
    float*  cnt    = sums + (size_t)N_GRAPHS * HID;               // 1024

    hipMemsetAsync(cursor, 0, N_NODES * sizeof(int), stream);
    hipMemsetAsync(sums, 0, ((size_t)N_GRAPHS * HID + N_GRAPHS) * sizeof(float), stream);

    k_input_proj<<<(N_NODES * HID) / 256, 256, 0, stream>>>(x, inW, inb, h0);

    // CSR build (once per launch, reused across 4 layers)
    k_hist<<<N_EDGES / 256, 256, 0, stream>>>(ei, cursor);
    k_scan<<<1, SCAN_THREADS, 0, stream>>>(cursor, row_ptr);
    k_scatter<<<N_EDGES / 256, 256, 0, stream>>>(ei, ea, cursor, edata);

    float* hin = h0;
    float* hout = h1;
    for (int l = 0; l < LAYERS; ++l) {
        k_node_update<<<N_NODES / 32, 256, 0, stream>>>(
            edata, row_ptr, edgeW + l * 3 * HID, edgeb + l * HID, hin, hout,
            w1 + l * HID * HID, b1 + l * HID, w2 + l * HID * HID, b2 + l * HID,
            gamma + l * HID, beta + l * HID);
        float* tmp = hin; hin = hout; hout = tmp;
    }
    // after 4 swaps, final h is back in h0 (== hin)

    k_pool<<<(N_NODES + 127) / 128, 128, 0, stream>>>(hin, batch, sums, cnt);
    k_head<<<N_GRAPHS, 128, 0, stream>>>(sums, cnt, fcW1, fcb1, fcW2, fcb2,
                                         fcW3, fcb3, out);
}

// Round 3
// 1838.292 us; speedup vs baseline: 6.3902x; 1.2755x over previous
//
#include <hip/hip_runtime.h>

#define N_NODES 100000
#define N_EDGES 1600000
#define N_GRAPHS 1024
#define HID 128
#define LAYERS 4
#define LN_EPS 1e-5f
#define SCAN_THREADS 1024
#define SCAN_CHUNK 98  // ceil(100000/1024)
#define LPAD (HID + 4)

// ---------------- input projection: h = x @ inW + inb ----------------
__global__ __launch_bounds__(256) void k_input_proj(
    const float* __restrict__ x, const float* __restrict__ inW,
    const float* __restrict__ inb, float* __restrict__ h) {
    int idx = blockIdx.x * 256 + threadIdx.x;  // over N_NODES*HID (exact)
    int n = idx >> 7, c = idx & 127;
    const float* xr = x + n * 7;
    float s = inb[c];
#pragma unroll
    for (int k = 0; k < 7; ++k) s += xr[k] * inW[k * HID + c];
    h[idx] = s;
}

// ---------------- CSR build: histogram of dst ------------------------
__global__ __launch_bounds__(256) void k_hist(
    const int* __restrict__ ei, int* __restrict__ deg) {
    int e = blockIdx.x * 256 + threadIdx.x;  // N_EDGES exact
    atomicAdd(&deg[ei[N_EDGES + e]], 1);
}

// ---------------- CSR build: single-block exclusive scan -------------
__global__ __launch_bounds__(SCAN_THREADS) void k_scan(
    int* __restrict__ cursor, int* __restrict__ row_ptr) {
    __shared__ int part[SCAN_THREADS];
    const int t = threadIdx.x;
    const int base = t * SCAN_CHUNK;
    int s = 0;
    for (int i = 0; i < SCAN_CHUNK; ++i) {
        int idx = base + i;
        if (idx < N_NODES) s += cursor[idx];
    }
    part[t] = s;
    __syncthreads();
    for (int off = 1; off < SCAN_THREADS; off <<= 1) {
        int v = 0;
        if (t >= off) v = part[t - off];
        __syncthreads();
        if (t >= off) part[t] += v;
        __syncthreads();
    }
    int run = (t == 0) ? 0 : part[t - 1];
    for (int i = 0; i < SCAN_CHUNK; ++i) {
        int idx = base + i;
        if (idx < N_NODES) {
            int d = cursor[idx];
            row_ptr[idx] = run;
            cursor[idx] = run;
            run += d;
        }
    }
    if (t == 0) row_ptr[N_NODES] = N_EDGES;
}

// ---------------- CSR build: scatter edges into sorted slots ---------
__global__ __launch_bounds__(256) void k_scatter(
    const int* __restrict__ ei, const float* __restrict__ ea,
    int* __restrict__ cursor, float4* __restrict__ edata) {
    int e = blockIdx.x * 256 + threadIdx.x;  // N_EDGES exact
    const int src = ei[e];
    const int dst = ei[N_EDGES + e];
    const int pos = atomicAdd(&cursor[dst], 1);
    edata[pos] = make_float4(ea[e * 3 + 0], ea[e * 3 + 1], ea[e * 3 + 2],
                             __int_as_float(src));
}

// ------- fused gather-aggregate + MLP + residual + layernorm ---------
// 256 threads = 4 waves; each wave owns 4 nodes end-to-end (rows r0..r0+3).
// No cross-wave LDS dependencies -> NO __syncthreads in the whole kernel.
__global__ __launch_bounds__(256) void k_node_update(
    const float4* __restrict__ edata, const int* __restrict__ row_ptr,
    const float* __restrict__ eW, const float* __restrict__ eb,
    const float* __restrict__ hin, float* __restrict__ hout,
    const float* __restrict__ w1, const float* __restrict__ b1,
    const float* __restrict__ w2, const float* __restrict__ b2,
    const float* __restrict__ gamma, const float* __restrict__ beta) {
    __shared__ float gt[16][LPAD];
    __shared__ float t1[16][LPAD];
    const int wave = threadIdx.x >> 6;
    const int lane = threadIdx.x & 63;
    const int c2 = lane * 2;            // this thread's 2 columns
    const int n0 = blockIdx.x * 16;
    const int r0 = wave * 4;            // this wave's first row slot

    // ---- phase 1: gt[r] = hin[n] + sum_e relu(hin[src] + edgeproj) ----
    {
        const float2 ew0 = *(const float2*)(eW + 0 * HID + c2);
        const float2 ew1 = *(const float2*)(eW + 1 * HID + c2);
        const float2 ew2 = *(const float2*)(eW + 2 * HID + c2);
        const float2 ebv = *(const float2*)(eb + c2);
        for (int s = 0; s < 4; ++s) {
            const int n = n0 + r0 + s;
            const float2 hv0 = *(const float2*)(hin + (long)n * HID + c2);
            float ax = hv0.x, ay = hv0.y;
            const int e0 = row_ptr[n], e1 = row_ptr[n + 1];
            int e = e0;
            // unroll x4: 4 independent edata + 4 independent hin loads in flight
            for (; e + 4 <= e1; e += 4) {
                const float4 ed0 = edata[e + 0];
                const float4 ed1 = edata[e + 1];
                const float4 ed2 = edata[e + 2];
                const float4 ed3 = edata[e + 3];
                const int s0 = __builtin_amdgcn_readfirstlane(__float_as_int(ed0.w));
                const int s1 = __builtin_amdgcn_readfirstlane(__float_as_int(ed1.w));
                const int s2 = __builtin_amdgcn_readfirstlane(__float_as_int(ed2.w));
                const int s3 = __builtin_amdgcn_readfirstlane(__float_as_int(ed3.w));
                const float2 g0 = *(const float2*)(hin + (long)s0 * HID + c2);
                const float2 g1 = *(const float2*)(hin + (long)s1 * HID + c2);
                const float2 g2 = *(const float2*)(hin + (long)s2 * HID + c2);
                const float2 g3 = *(const float2*)(hin + (long)s3 * HID + c2);
                ax += fmaxf(g0.x + ed0.x * ew0.x + ed0.y * ew1.x + ed0.z * ew2.x + ebv.x, 0.f);
                ay += fmaxf(g0.y + ed0.x * ew0.y + ed0.y * ew1.y + ed0.z * ew2.y + ebv.y, 0.f);
                ax += fmaxf(g1.x + ed1.x * ew0.x + ed1.y * ew1.x + ed1.z * ew2.x + ebv.x, 0.f);
                ay += fmaxf(g1.y + ed1.x * ew0.y + ed1.y * ew1.y + ed1.z * ew2.y + ebv.y, 0.f);
                ax += fmaxf(g2.x + ed2.x * ew0.x + ed2.y * ew1.x + ed2.z * ew2.x + ebv.x, 0.f);
                ay += fmaxf(g2.y + ed2.x * ew0.y + ed2.y * ew1.y + ed2.z * ew2.y + ebv.y, 0.f);
                ax += fmaxf(g3.x + ed3.x * ew0.x + ed3.y * ew1.x + ed3.z * ew2.x + ebv.x, 0.f);
                ay += fmaxf(g3.y + ed3.x * ew0.y + ed3.y * ew1.y + ed3.z * ew2.y + ebv.y, 0.f);
            }
            for (; e < e1; ++e) {
                const float4 ed = edata[e];
                const int sr = __builtin_amdgcn_readfirstlane(__float_as_int(ed.w));
                const float2 gv = *(const float2*)(hin + (long)sr * HID + c2);
                ax += fmaxf(gv.x + ed.x * ew0.x + ed.y * ew1.x + ed.z * ew2.x + ebv.x, 0.f);
                ay += fmaxf(gv.y + ed.x * ew0.y + ed.y * ew1.y + ed.z * ew2.y + ebv.y, 0.f);
            }
            *(float2*)&gt[r0 + s][c2] = make_float2(ax, ay);
        }
    }
    // same-wave LDS producer/consumer: hardware-ordered, no barrier needed

    // ---- phase 2: t1[r] = relu(gt[r] @ w1 + b1), cols c2,c2+1 ----
    {
        float acc[4][2];
        const float2 bv = *(const float2*)(b1 + c2);
#pragma unroll
        for (int r = 0; r < 4; ++r) { acc[r][0] = bv.x; acc[r][1] = bv.y; }
#pragma unroll 4
        for (int k = 0; k < HID; ++k) {
            const float2 w = *(const float2*)(w1 + k * HID + c2);
            const float g0 = gt[r0 + 0][k];
            const float g1 = gt[r0 + 1][k];
            const float g2 = gt[r0 + 2][k];
            const float g3 = gt[r0 + 3][k];
            acc[0][0] += g0 * w.x; acc[0][1] += g0 * w.y;
            acc[1][0] += g1 * w.x; acc[1][1] += g1 * w.y;
            acc[2][0] += g2 * w.x; acc[2][1] += g2 * w.y;
            acc[3][0] += g3 * w.x; acc[3][1] += g3 * w.y;
        }
#pragma unroll
        for (int r = 0; r < 4; ++r) {
            *(float2*)&t1[r0 + r][c2] =
                make_float2(fmaxf(acc[r][0], 0.f), fmaxf(acc[r][1], 0.f));
        }
    }

    // ---- phase 3: u = hin + relu(t1 @ w2 + b2); fused layernorm ----
    {
        float acc[4][2];
        const float2 bv = *(const float2*)(b2 + c2);
#pragma unroll
        for (int r = 0; r < 4; ++r) { acc[r][0] = bv.x; acc[r][1] = bv.y; }
#pragma unroll 4
        for (int k = 0; k < HID; ++k) {
            const float2 w = *(const float2*)(w2 + k * HID + c2);
            const float v0 = t1[r0 + 0][k];
            const float v1 = t1[r0 + 1][k];
            const float v2 = t1[r0 + 2][k];
            const float v3 = t1[r0 + 3][k];
            acc[0][0] += v0 * w.x; acc[0][1] += v0 * w.y;
            acc[1][0] += v1 * w.x; acc[1][1] += v1 * w.y;
            acc[2][0] += v2 * w.x; acc[2][1] += v2 * w.y;
            acc[3][0] += v3 * w.x; acc[3][1] += v3 * w.y;
        }
        const float2 gmv = *(const float2*)(gamma + c2);
        const float2 btv = *(const float2*)(beta + c2);
#pragma unroll
        for (int r = 0; r < 4; ++r) {
            const int n = n0 + r0 + r;
            const float2 hv = *(const float2*)(hin + (long)n * HID + c2);
            const float ux = hv.x + fmaxf(acc[r][0], 0.f);
            const float uy = hv.y + fmaxf(acc[r][1], 0.f);
            // wave-wide LN stats (all 64 lanes hold cols of this row)
            float s = ux + uy, s2 = ux * ux + uy * uy;
#pragma unroll
            for (int off = 1; off < 64; off <<= 1) {
                s += __shfl_xor(s, off);
                s2 += __shfl_xor(s2, off);
            }
            const float mu = s * (1.f / HID);
            const float var = s2 * (1.f / HID) - mu * mu;
            const float inv = rsqrtf(var + LN_EPS);
            float2 o;
            o.x = (ux - mu) * inv * gmv.x + btv.x;
            o.y = (uy - mu) * inv * gmv.y + btv.y;
            *(float2*)(hout + (long)n * HID + c2) = o;
        }
    }
}

// -------- global mean pool: segmented reduction (batch is sorted) ----
__global__ __launch_bounds__(128) void k_pool(
    const float* __restrict__ h, const int* __restrict__ batch,
    float* __restrict__ sums, float* __restrict__ cnt) {
    const int c = threadIdx.x;
    const int n0 = blockIdx.x * 128;
    if (n0 >= N_NODES) return;
    const int nend = min(n0 + 128, N_NODES);
    int cur = batch[n0];
    float acc = 0.f;
    int runlen = 0;
    for (int n = n0; n < nend; ++n) {
        const int b = batch[n];
        if (b != cur) {
            atomicAdd(&sums[(long)cur * HID + c], acc);
            if (c == 0) atomicAdd(&cnt[cur], (float)runlen);
            acc = 0.f;
            runlen = 0;
            cur = b;
        }
        acc += h[(long)n * HID + c];
        ++runlen;
    }
    atomicAdd(&sums[(long)cur * HID + c], acc);
    if (c == 0) atomicAdd(&cnt[cur], (float)runlen);
}

// ---------------- head: 1 block per graph ----------------------------
__global__ __launch_bounds__(128) void k_head(
    const float* __restrict__ sums, const float* __restrict__ cnt,
    const float* __restrict__ fcW1, const float* __restrict__ fcb1,
    const float* __restrict__ fcW2, const float* __restrict__ fcb2,
    const float* __restrict__ fcW3, const float* __restrict__ fcb3,
    float* __restrict__ out) {
    __shared__ float p[HID];
    __shared__ float o1[HID];
    __shared__ float o2[64];
    const int g = blockIdx.x, t = threadIdx.x;
    const float c = fmaxf(cnt[g], 1.0f);
    p[t] = sums[g * HID + t] / c;
    __syncthreads();
    float s = fcb1[t];
    for (int k = 0; k < HID; ++k) s += p[k] * fcW1[k * HID + t];
    o1[t] = fmaxf(s, 0.f);
    __syncthreads();
    if (t < 64) {
        float s2 = fcb2[t];
        for (int k = 0; k < HID; ++k) s2 += o1[k] * fcW2[k * 64 + t];
        o2[t] = fmaxf(s2, 0.f);
    }
    __syncthreads();
    if (t < 64) {
        float v = o2[t] * fcW3[t];
#pragma unroll
        for (int off = 32; off > 0; off >>= 1) v += __shfl_down(v, off);
        if (t == 0) out[g] = v + fcb3[0];
    }
}

extern "C" void kernel_launch(void* const* d_in, const int* in_sizes, int n_in,
                              void* d_out, int out_size, void* d_ws, size_t ws_size,
                              hipStream_t stream) {
    const float* x    = (const float*)d_in[0];
    const int*   ei   = (const int*)d_in[1];
    const float* ea   = (const float*)d_in[2];
    const int*   batch= (const int*)d_in[3];
    const float* inW  = (const float*)d_in[4];
    const float* inb  = (const float*)d_in[5];
    const float* edgeW= (const float*)d_in[6];
    const float* edgeb= (const float*)d_in[7];
    const float* w1   = (const float*)d_in[8];
    const float* b1   = (const float*)d_in[9];
    const float* w2   = (const float*)d_in[10];
    const float* b2   = (const float*)d_in[11];
    const float* gamma= (const float*)d_in[12];
    const float* beta = (const float*)d_in[13];
    const float* fcW1 = (const float*)d_in[14];
    const float* fcb1 = (const float*)d_in[15];
    const float* fcW2 = (const float*)d_in[16];
    const float* fcb2 = (const float*)d_in[17];
    const float* fcW3 = (const float*)d_in[18];
    const float* fcb3 = (const float*)d_in[19];
    float* out = (float*)d_out;

    // workspace layout (float4-aligned first)
    float4* edata  = (float4*)d_ws;                               // 1.6M float4
    float*  h0     = (float*)(edata + N_EDGES);                   // 12.8M f32
    float*  h1     = h0 + (size_t)N_NODES * HID;                  // 12.8M f32
    int*    row_ptr= (int*)(h1 + (size_t)N_NODES * HID);          // 100001
    int*    cursor = row_ptr + (N_NODES + 1);                     // 100000
    float*  sums   = (float*)(cursor + N_NODES);                  // 1024*128
    float*  cnt    = sums + (size_t)N_GRAPHS * HID;               // 1024

    hipMemsetAsync(cursor, 0, N_NODES * sizeof(int), stream);
    hipMemsetAsync(sums, 0, ((size_t)N_GRAPHS * HID + N_GRAPHS) * sizeof(float), stream);

    k_input_proj<<<(N_NODES * HID) / 256, 256, 0, stream>>>(x, inW, inb, h0);

    // CSR build (once per launch, reused across 4 layers)
    k_hist<<<N_EDGES / 256, 256, 0, stream>>>(ei, cursor);
    k_scan<<<1, SCAN_THREADS, 0, stream>>>(cursor, row_ptr);
    k_scatter<<<N_EDGES / 256, 256, 0, stream>>>(ei, ea, cursor, edata);

    float* hin = h0;
    float* hout = h1;
    for (int l = 0; l < LAYERS; ++l) {
        k_node_update<<<N_NODES / 16, 256, 0, stream>>>(
            edata, row_ptr, edgeW + l * 3 * HID, edgeb + l * HID, hin, hout,
            w1 + l * HID * HID, b1 + l * HID, w2 + l * HID * HID, b2 + l * HID,
            gamma + l * HID, beta + l * HID);
        float* tmp = hin; hin = hout; hout = tmp;
    }
    // after 4 swaps, final h is back in h0 (== hin)

    k_pool<<<(N_NODES + 127) / 128, 128, 0, stream>>>(hin, batch, sums, cnt);
    k_head<<<N_GRAPHS, 128, 0, stream>>>(sums, cnt, fcW1, fcb1, fcW2, fcb2,
                                         fcW3, fcb3, out);
}